// Round 4
// baseline (231.365 us; speedup 1.0000x reference)
//
#include <hip/hip_runtime.h>

#define NUM_NODES 200000
#define DIM 128
#define BATCH 1024
#define K_NEG 5
#define CAP 16
#define JW 96             /* j-columns per wave (3 MFMA B-subtiles) */
#define BN (4 * JW)       /* j-columns per block = 384 */
#define THRESH 0.7f
#define FILL (-1.0e9f)

typedef __attribute__((ext_vector_type(8))) short short8;
typedef __attribute__((ext_vector_type(16))) float f32x16;

// round-to-nearest-even float -> bf16 bits (finite inputs only)
__device__ __forceinline__ unsigned short f2bf(float x) {
  unsigned u = __builtin_bit_cast(unsigned, x);
  return (unsigned short)((u + 0x7fffu + ((u >> 16) & 1u)) >> 16);
}

// ---------------- Threefry-2x32 (JAX-compatible) ----------------
__device__ __forceinline__ void tf2x32(unsigned k0, unsigned k1,
                                       unsigned x0, unsigned x1,
                                       unsigned* o0, unsigned* o1) {
  unsigned ks2 = k0 ^ k1 ^ 0x1BD11BDAu;
  unsigned v0 = x0 + k0, v1 = x1 + k1;
#define TFR(r) { v0 += v1; v1 = (v1 << r) | (v1 >> (32 - r)); v1 ^= v0; }
  TFR(13) TFR(15) TFR(26) TFR(6)   v0 += k1;  v1 += ks2 + 1u;
  TFR(17) TFR(29) TFR(16) TFR(24)  v0 += ks2; v1 += k0 + 2u;
  TFR(13) TFR(15) TFR(26) TFR(6)   v0 += k0;  v1 += k1 + 3u;
  TFR(17) TFR(29) TFR(16) TFR(24)  v0 += k1;  v1 += ks2 + 4u;
  TFR(13) TFR(15) TFR(26) TFR(6)   v0 += ks2; v1 += k0 + 5u;
#undef TFR
  *o0 = v0; *o1 = v1;
}

__device__ __forceinline__ unsigned rbits32(unsigned ka, unsigned kb, unsigned m) {
  unsigned o0, o1;
  tf2x32(ka, kb, 0u, m, &o0, &o1);
  return o0 ^ o1;
}

// ---- kernel 1: normalize src rows -> bf16 A-fragments (fragment-major), zero counters
// Fragment layout: chunk index ((ms*8 + ks)*64 + lane64) is 8 bf16 (16 B) holding
// A[row = ms*32 + (lane64&31)][col = ks*16 + (lane64>>5)*8 + t], t=0..7.
__global__ void prep_kernel(const float* __restrict__ memory,
                            const int* __restrict__ src_nodes,
                            unsigned short* __restrict__ s16f,
                            int* __restrict__ cand_cnt) {
  int tid = threadIdx.x;
  int gid = blockIdx.x * 256 + tid;
  if (gid < BATCH) cand_cnt[gid] = 0;
  int row = blockIdx.x * 4 + (tid >> 6);   // 256 blocks x 4 waves = 1024 rows
  int L = tid & 63;                        // lane within the row's wave; cols 2L,2L+1
  int s = src_nodes[row];
  float2 v = ((const float2*)(memory + (size_t)s * DIM))[L];
  float ss = v.x * v.x + v.y * v.y;
#pragma unroll
  for (int off = 32; off > 0; off >>= 1) ss += __shfl_xor(ss, off);
  float inv = 1.0f / fmaxf(sqrtf(ss), 1e-12f);
  unsigned p = (unsigned)f2bf(v.x * inv) | ((unsigned)f2bf(v.y * inv) << 16);
  int ms = row >> 5, l32 = row & 31;
  int c = L >> 2;             // col chunk = col/8
  int ks = c >> 1, half = c & 1;
  ((unsigned*)s16f)[(((ms * 8 + ks) * 64) + half * 32 + l32) * 4 + (L & 3)] = p;
}

// ---- kernel 2: barrier-free MFMA sim scan, 96 j-cols/wave, collect >0.7 hits ----
// __launch_bounds__(256,1): VGPR cap 512 so the ~230-reg working set (96 B-frag +
// 48 acc + 64 A-dbuf) allocates without spilling; occupancy lands at 2 waves/SIMD.
__global__ __launch_bounds__(256, 1) void sim_scan_kernel(
    const float* __restrict__ memory,
    const unsigned short* __restrict__ s16f,
    const int* __restrict__ dst_nodes,
    int* __restrict__ cand_cnt,
    float* __restrict__ cand_val,
    int* __restrict__ cand_idx) {
  int tid = threadIdx.x;
  int wid = tid >> 6;
  int lane = tid & 63;
  int half = lane >> 5;
  int l32 = lane & 31;
  int jb = blockIdx.x * BN + wid * JW;   // wave's 96-column base

  // ---- build 3 B-subtile fragment sets in registers (L2-normalized rows -> bf16) ----
  short8 bf[3][8];
#pragma unroll
  for (int js = 0; js < 3; ++js) {
    int j = jb + js * 32 + l32;
    bool jv = (j < NUM_NODES);
    const float4* rp4 = (const float4*)(memory + (size_t)j * DIM);
    float4 q[16];
#pragma unroll
    for (int ks = 0; ks < 8; ++ks) {
      // lane (l32,half) holds cols ks*16 + half*8 + 0..7 of row j
      q[ks * 2]     = jv ? rp4[ks * 4 + half * 2]     : make_float4(0.f, 0.f, 0.f, 0.f);
      q[ks * 2 + 1] = jv ? rp4[ks * 4 + half * 2 + 1] : make_float4(0.f, 0.f, 0.f, 0.f);
    }
    float ss = 0.0f;
#pragma unroll
    for (int i = 0; i < 16; ++i)
      ss += q[i].x * q[i].x + q[i].y * q[i].y + q[i].z * q[i].z + q[i].w * q[i].w;
    ss += __shfl_xor(ss, 32);            // combine the two half-rows
    float inv = 1.0f / fmaxf(sqrtf(ss), 1e-12f);
#pragma unroll
    for (int ks = 0; ks < 8; ++ks) {
      float4 a = q[ks * 2], b = q[ks * 2 + 1];
      short8 f;
      f[0] = (short)f2bf(a.x * inv); f[1] = (short)f2bf(a.y * inv);
      f[2] = (short)f2bf(a.z * inv); f[3] = (short)f2bf(a.w * inv);
      f[4] = (short)f2bf(b.x * inv); f[5] = (short)f2bf(b.y * inv);
      f[6] = (short)f2bf(b.z * inv); f[7] = (short)f2bf(b.w * inv);
      bf[js][ks] = f;
    }
  }

  const short8* __restrict__ af = (const short8*)s16f;
  short8 a0[8], a1[8];
#pragma unroll
  for (int ks = 0; ks < 8; ++ks) a0[ks] = af[ks * 64 + lane];

#define COMPUTE(ABUF, MSV)                                                            \
  {                                                                                   \
    f32x16 acc[3];                                                                    \
    _Pragma("unroll") for (int js = 0; js < 3; ++js)                                  \
        _Pragma("unroll") for (int i = 0; i < 16; ++i) acc[js][i] = 0.0f;             \
    _Pragma("unroll") for (int ks = 0; ks < 8; ++ks)                                  \
        _Pragma("unroll") for (int js = 0; js < 3; ++js)                              \
            acc[js] = __builtin_amdgcn_mfma_f32_32x32x16_bf16(ABUF[ks], bf[js][ks],   \
                                                              acc[js], 0, 0, 0);      \
    float vm = acc[0][0];                                                             \
    _Pragma("unroll") for (int js = 0; js < 3; ++js)                                  \
        _Pragma("unroll") for (int i = 0; i < 16; ++i) vm = fmaxf(vm, acc[js][i]);    \
    if (vm > THRESH) {                                                                \
      _Pragma("unroll") for (int js = 0; js < 3; ++js) {                              \
        int gj = jb + js * 32 + l32;                                                  \
        _Pragma("unroll") for (int r = 0; r < 16; ++r) {                              \
          float v = acc[js][r];                                                       \
          if (v > THRESH) {                                                           \
            int gi = (MSV) * 32 + (r & 3) + 8 * (r >> 2) + 4 * half;                  \
            if (gj < NUM_NODES && gj != dst_nodes[gi]) {                              \
              int p = atomicAdd(&cand_cnt[gi], 1);                                    \
              if (p < CAP) {                                                          \
                cand_val[gi * CAP + p] = v;                                           \
                cand_idx[gi * CAP + p] = gj;                                          \
              }                                                                       \
            }                                                                         \
          }                                                                           \
        }                                                                             \
      }                                                                               \
    }                                                                                 \
  }

  for (int ms = 0; ms < 32; ms += 2) {
    // issue loads for ms+1 before computing ms
#pragma unroll
    for (int ks = 0; ks < 8; ++ks) a1[ks] = af[((ms + 1) * 8 + ks) * 64 + lane];
    COMPUTE(a0, ms)
    if (ms + 2 < 32) {
#pragma unroll
      for (int ks = 0; ks < 8; ++ks) a0[ks] = af[((ms + 2) * 8 + ks) * 64 + lane];
    }
    COMPUTE(a1, ms + 1)
  }
#undef COMPUTE
}

// ---- kernel 3: top-5 per row, threefry negatives, assemble ----
__global__ void finalize_kernel(const int* __restrict__ src_nodes,
                                const int* __restrict__ dst_nodes,
                                const float* __restrict__ labels,
                                const float* __restrict__ ts,
                                const int* __restrict__ cand_cnt,
                                const float* __restrict__ cand_val,
                                const int* __restrict__ cand_idx,
                                float* __restrict__ out) {
  int r = blockIdx.x * 256 + threadIdx.x;
  if (r >= BATCH) return;
  const int TOT = BATCH + BATCH * K_NEG;  // 6144
  int srcv = src_nodes[r];
  float tsv = ts[r];
  out[r] = (float)srcv;
  out[TOT + r] = (float)dst_nodes[r];
  float l = labels[r];
  out[2 * TOT + r] = l * 0.9f + (1.0f - l) * 0.1f;
  out[3 * TOT + r] = tsv;

  int cnt = cand_cnt[r];
  cnt = cnt < CAP ? cnt : CAP;
  float cv[CAP]; int ci[CAP];
  for (int i = 0; i < cnt; ++i) { cv[i] = cand_val[r * CAP + i]; ci[i] = cand_idx[r * CAP + i]; }

  // jax.random.split(key(42)) — partitionable/foldlike: k_i = threefry(key, 0, i)
  unsigned k1a, k1b, k2a, k2b;
  tf2x32(0u, 42u, 0u, 0u, &k1a, &k1b);
  tf2x32(0u, 42u, 0u, 1u, &k2a, &k2b);

  const unsigned span = 200000u;
  const unsigned mult = 167296u;  // 2^32 % span

  for (int s = 0; s < K_NEG; ++s) {
    int sel = -1;
    for (int i = 0; i < cnt; ++i)
      if (sel < 0 || cv[i] > cv[sel] || (cv[i] == cv[sel] && ci[i] < ci[sel])) sel = i;
    float v = FILL; int idx = 0;
    if (sel >= 0) { v = cv[sel]; idx = ci[sel]; cv[sel] = FILL; ci[sel] = 0x7fffffff; }
    bool is_real = v > (FILL + 1.0f);

    unsigned m = (unsigned)(r * K_NEG + s);
    unsigned hi = rbits32(k1a, k1b, m);
    unsigned lo = rbits32(k2a, k2b, m);
    unsigned off = ((hi % span) * mult + (lo % span)) % span;  // uint32 wrap, as JAX
    int rd = (int)off;
    if (rd == srcv) rd = (rd + 1) % NUM_NODES;
    int fd = is_real ? idx : rd;

    int mi = (int)m;
    out[BATCH + mi] = (float)srcv;
    out[TOT + BATCH + mi] = (float)fd;
    out[2 * TOT + BATCH + mi] = 0.1f;   // smoothing of label 0
    out[3 * TOT + BATCH + mi] = tsv;
    out[4 * TOT + mi] = v;
  }
}

extern "C" void kernel_launch(void* const* d_in, const int* in_sizes, int n_in,
                              void* d_out, int out_size, void* d_ws, size_t ws_size,
                              hipStream_t stream) {
  const int* src = (const int*)d_in[0];
  const int* dst = (const int*)d_in[1];
  const float* labels = (const float*)d_in[2];
  const float* ts = (const float*)d_in[3];
  const float* memory = (const float*)d_in[4];
  float* out = (float*)d_out;

  char* ws = (char*)d_ws;
  unsigned short* s16f = (unsigned short*)ws;       // 1024*128*2 = 262144 B (fragment-major)
  int* cand_cnt = (int*)(ws + 262144);              // 4096 B
  float* cand_val = (float*)(ws + 266240);          // 65536 B
  int* cand_idx = (int*)(ws + 331776);              // 65536 B

  prep_kernel<<<256, 256, 0, stream>>>(memory, src, s16f, cand_cnt);
  int jblocks = (NUM_NODES + BN - 1) / BN;          // 521
  sim_scan_kernel<<<jblocks, 256, 0, stream>>>(memory, s16f, dst, cand_cnt, cand_val, cand_idx);
  finalize_kernel<<<(BATCH + 255) / 256, 256, 0, stream>>>(src, dst, labels, ts,
                                                           cand_cnt, cand_val, cand_idx, out);
}

// Round 5
// 229.158 us; speedup vs baseline: 1.0096x; 1.0096x over previous
//
#include <hip/hip_runtime.h>

#define NUM_NODES 200000
#define DIM 128
#define BATCH 1024
#define K_NEG 5
#define CAP 16
#define JW 64             /* j-columns per wave (2 MFMA B-subtiles) */
#define BN (4 * JW)       /* j-columns per block = 256 */
#define THRESH 0.7f
#define FILL (-1.0e9f)

typedef __attribute__((ext_vector_type(8))) short short8;
typedef __attribute__((ext_vector_type(16))) float f32x16;

// round-to-nearest-even float -> bf16 bits (finite inputs only)
__device__ __forceinline__ unsigned short f2bf(float x) {
  unsigned u = __builtin_bit_cast(unsigned, x);
  return (unsigned short)((u + 0x7fffu + ((u >> 16) & 1u)) >> 16);
}

// ---------------- Threefry-2x32 (JAX-compatible) ----------------
__device__ __forceinline__ void tf2x32(unsigned k0, unsigned k1,
                                       unsigned x0, unsigned x1,
                                       unsigned* o0, unsigned* o1) {
  unsigned ks2 = k0 ^ k1 ^ 0x1BD11BDAu;
  unsigned v0 = x0 + k0, v1 = x1 + k1;
#define TFR(r) { v0 += v1; v1 = (v1 << r) | (v1 >> (32 - r)); v1 ^= v0; }
  TFR(13) TFR(15) TFR(26) TFR(6)   v0 += k1;  v1 += ks2 + 1u;
  TFR(17) TFR(29) TFR(16) TFR(24)  v0 += ks2; v1 += k0 + 2u;
  TFR(13) TFR(15) TFR(26) TFR(6)   v0 += k0;  v1 += k1 + 3u;
  TFR(17) TFR(29) TFR(16) TFR(24)  v0 += k1;  v1 += ks2 + 4u;
  TFR(13) TFR(15) TFR(26) TFR(6)   v0 += ks2; v1 += k0 + 5u;
#undef TFR
  *o0 = v0; *o1 = v1;
}

__device__ __forceinline__ unsigned rbits32(unsigned ka, unsigned kb, unsigned m) {
  unsigned o0, o1;
  tf2x32(ka, kb, 0u, m, &o0, &o1);
  return o0 ^ o1;
}

// ---- kernel 1: normalize src rows -> bf16 A-fragments (fragment-major), zero counters
// Fragment layout: chunk index ((ms*8 + ks)*64 + lane64) is 8 bf16 (16 B) holding
// A[row = ms*32 + (lane64&31)][col = ks*16 + (lane64>>5)*8 + t], t=0..7.
__global__ void prep_kernel(const float* __restrict__ memory,
                            const int* __restrict__ src_nodes,
                            unsigned short* __restrict__ s16f,
                            int* __restrict__ cand_cnt) {
  int tid = threadIdx.x;
  int gid = blockIdx.x * 256 + tid;
  if (gid < BATCH) cand_cnt[gid] = 0;
  int row = blockIdx.x * 4 + (tid >> 6);   // 256 blocks x 4 waves = 1024 rows
  int L = tid & 63;                        // lane within the row's wave; cols 2L,2L+1
  int s = src_nodes[row];
  float2 v = ((const float2*)(memory + (size_t)s * DIM))[L];
  float ss = v.x * v.x + v.y * v.y;
#pragma unroll
  for (int off = 32; off > 0; off >>= 1) ss += __shfl_xor(ss, off);
  float inv = 1.0f / fmaxf(sqrtf(ss), 1e-12f);
  unsigned p = (unsigned)f2bf(v.x * inv) | ((unsigned)f2bf(v.y * inv) << 16);
  int ms = row >> 5, l32 = row & 31;
  int c = L >> 2;             // col chunk = col/8
  int ks = c >> 1, half = c & 1;
  ((unsigned*)s16f)[(((ms * 8 + ks) * 64) + half * 32 + l32) * 4 + (L & 3)] = p;
}

// ---- kernel 2: MFMA sim scan; A phase-staged in LDS (4 x 64 KB), B in regs ----
// Budget: ~64 VGPR (B-frags) + 32 AGPR (acc) + 32 (A regs) + misc < 256 combined;
// 64 KB LDS -> 2 blocks/CU -> 2 waves/SIMD for cross-wave MFMA/VALU overlap (m114).
__global__ __launch_bounds__(256, 2) void sim_scan_kernel(
    const float* __restrict__ memory,
    const unsigned short* __restrict__ s16f,
    const int* __restrict__ dst_nodes,
    int* __restrict__ cand_cnt,
    float* __restrict__ cand_val,
    int* __restrict__ cand_idx) {
  __shared__ short8 aT[4096];   // 64 KB: one phase = 8 ms-subtiles of A fragments
  int tid = threadIdx.x;
  int wid = tid >> 6;
  int lane = tid & 63;
  int half = lane >> 5;
  int l32 = lane & 31;
  int jb = blockIdx.x * BN + wid * JW;   // wave's 64-column base

  // ---- build 2 B-subtile fragment sets in registers (L2-normalized rows -> bf16) ----
  short8 bf[2][8];
#pragma unroll
  for (int js = 0; js < 2; ++js) {
    int j = jb + js * 32 + l32;
    bool jv = (j < NUM_NODES);
    const float4* rp4 = (const float4*)(memory + (size_t)j * DIM);
    float4 q[16];
#pragma unroll
    for (int ks = 0; ks < 8; ++ks) {
      // lane (l32,half) holds cols ks*16 + half*8 + 0..7 of row j
      q[ks * 2]     = jv ? rp4[ks * 4 + half * 2]     : make_float4(0.f, 0.f, 0.f, 0.f);
      q[ks * 2 + 1] = jv ? rp4[ks * 4 + half * 2 + 1] : make_float4(0.f, 0.f, 0.f, 0.f);
    }
    float ss = 0.0f;
#pragma unroll
    for (int i = 0; i < 16; ++i)
      ss += q[i].x * q[i].x + q[i].y * q[i].y + q[i].z * q[i].z + q[i].w * q[i].w;
    ss += __shfl_xor(ss, 32);            // combine the two half-rows
    float inv = 1.0f / fmaxf(sqrtf(ss), 1e-12f);
#pragma unroll
    for (int ks = 0; ks < 8; ++ks) {
      float4 a = q[ks * 2], b = q[ks * 2 + 1];
      short8 f;
      f[0] = (short)f2bf(a.x * inv); f[1] = (short)f2bf(a.y * inv);
      f[2] = (short)f2bf(a.z * inv); f[3] = (short)f2bf(a.w * inv);
      f[4] = (short)f2bf(b.x * inv); f[5] = (short)f2bf(b.y * inv);
      f[6] = (short)f2bf(b.z * inv); f[7] = (short)f2bf(b.w * inv);
      bf[js][ks] = f;
    }
  }

  const short8* __restrict__ afg = (const short8*)s16f;

  for (int p = 0; p < 4; ++p) {
    __syncthreads();                    // all waves done reading the previous phase
    // stage 64 KB phase: 16 contiguous 16B chunks per thread (coalesced + b128 writes)
#pragma unroll
    for (int c = 0; c < 16; ++c) {
      int idx = c * 256 + tid;
      aT[idx] = afg[p * 4096 + idx];
    }
    __syncthreads();                    // staged data visible

#pragma unroll
    for (int ml = 0; ml < 8; ++ml) {
      int ms = p * 8 + ml;
      short8 a[8];
#pragma unroll
      for (int ks = 0; ks < 8; ++ks) a[ks] = aT[(ml * 8 + ks) * 64 + lane];
      f32x16 acc0, acc1;
#pragma unroll
      for (int i = 0; i < 16; ++i) { acc0[i] = 0.0f; acc1[i] = 0.0f; }
#pragma unroll
      for (int ks = 0; ks < 8; ++ks) {
        acc0 = __builtin_amdgcn_mfma_f32_32x32x16_bf16(a[ks], bf[0][ks], acc0, 0, 0, 0);
        acc1 = __builtin_amdgcn_mfma_f32_32x32x16_bf16(a[ks], bf[1][ks], acc1, 0, 0, 0);
      }
      // hand max-tree over the 32 accumulator elements (rare-hit gate)
      float m[16];
#pragma unroll
      for (int i = 0; i < 16; ++i) m[i] = fmaxf(acc0[i], acc1[i]);
#pragma unroll
      for (int i = 0; i < 8; ++i) m[i] = fmaxf(m[i], m[i + 8]);
#pragma unroll
      for (int i = 0; i < 4; ++i) m[i] = fmaxf(m[i], m[i + 4]);
      float vm = fmaxf(fmaxf(m[0], m[1]), fmaxf(m[2], m[3]));
      if (vm > THRESH) {
        // C/D layout (m74/m101): col = lane&31, row = (reg&3) + 8*(reg>>2) + 4*(lane>>5)
#pragma unroll
        for (int js = 0; js < 2; ++js) {
          int gj = jb + js * 32 + l32;
#pragma unroll
          for (int r = 0; r < 16; ++r) {
            float v = (js == 0) ? acc0[r] : acc1[r];
            if (v > THRESH) {
              int gi = ms * 32 + (r & 3) + 8 * (r >> 2) + 4 * half;
              if (gj < NUM_NODES && gj != dst_nodes[gi]) {
                int pp = atomicAdd(&cand_cnt[gi], 1);
                if (pp < CAP) {
                  cand_val[gi * CAP + pp] = v;
                  cand_idx[gi * CAP + pp] = gj;
                }
              }
            }
          }
        }
      }
    }
  }
}

// ---- kernel 3: top-5 per row, threefry negatives, assemble ----
__global__ void finalize_kernel(const int* __restrict__ src_nodes,
                                const int* __restrict__ dst_nodes,
                                const float* __restrict__ labels,
                                const float* __restrict__ ts,
                                const int* __restrict__ cand_cnt,
                                const float* __restrict__ cand_val,
                                const int* __restrict__ cand_idx,
                                float* __restrict__ out) {
  int r = blockIdx.x * 256 + threadIdx.x;
  if (r >= BATCH) return;
  const int TOT = BATCH + BATCH * K_NEG;  // 6144
  int srcv = src_nodes[r];
  float tsv = ts[r];
  out[r] = (float)srcv;
  out[TOT + r] = (float)dst_nodes[r];
  float l = labels[r];
  out[2 * TOT + r] = l * 0.9f + (1.0f - l) * 0.1f;
  out[3 * TOT + r] = tsv;

  int cnt = cand_cnt[r];
  cnt = cnt < CAP ? cnt : CAP;
  float cv[CAP]; int ci[CAP];
  for (int i = 0; i < cnt; ++i) { cv[i] = cand_val[r * CAP + i]; ci[i] = cand_idx[r * CAP + i]; }

  // jax.random.split(key(42)) — partitionable/foldlike: k_i = threefry(key, 0, i)
  unsigned k1a, k1b, k2a, k2b;
  tf2x32(0u, 42u, 0u, 0u, &k1a, &k1b);
  tf2x32(0u, 42u, 0u, 1u, &k2a, &k2b);

  const unsigned span = 200000u;
  const unsigned mult = 167296u;  // 2^32 % span

  for (int s = 0; s < K_NEG; ++s) {
    int sel = -1;
    for (int i = 0; i < cnt; ++i)
      if (sel < 0 || cv[i] > cv[sel] || (cv[i] == cv[sel] && ci[i] < ci[sel])) sel = i;
    float v = FILL; int idx = 0;
    if (sel >= 0) { v = cv[sel]; idx = ci[sel]; cv[sel] = FILL; ci[sel] = 0x7fffffff; }
    bool is_real = v > (FILL + 1.0f);

    unsigned m = (unsigned)(r * K_NEG + s);
    unsigned hi = rbits32(k1a, k1b, m);
    unsigned lo = rbits32(k2a, k2b, m);
    unsigned off = ((hi % span) * mult + (lo % span)) % span;  // uint32 wrap, as JAX
    int rd = (int)off;
    if (rd == srcv) rd = (rd + 1) % NUM_NODES;
    int fd = is_real ? idx : rd;

    int mi = (int)m;
    out[BATCH + mi] = (float)srcv;
    out[TOT + BATCH + mi] = (float)fd;
    out[2 * TOT + BATCH + mi] = 0.1f;   // smoothing of label 0
    out[3 * TOT + BATCH + mi] = tsv;
    out[4 * TOT + mi] = v;
  }
}

extern "C" void kernel_launch(void* const* d_in, const int* in_sizes, int n_in,
                              void* d_out, int out_size, void* d_ws, size_t ws_size,
                              hipStream_t stream) {
  const int* src = (const int*)d_in[0];
  const int* dst = (const int*)d_in[1];
  const float* labels = (const float*)d_in[2];
  const float* ts = (const float*)d_in[3];
  const float* memory = (const float*)d_in[4];
  float* out = (float*)d_out;

  char* ws = (char*)d_ws;
  unsigned short* s16f = (unsigned short*)ws;       // 1024*128*2 = 262144 B (fragment-major)
  int* cand_cnt = (int*)(ws + 262144);              // 4096 B
  float* cand_val = (float*)(ws + 266240);          // 65536 B
  int* cand_idx = (int*)(ws + 331776);              // 65536 B

  prep_kernel<<<256, 256, 0, stream>>>(memory, src, s16f, cand_cnt);
  int jblocks = (NUM_NODES + BN - 1) / BN;          // 782
  sim_scan_kernel<<<jblocks, 256, 0, stream>>>(memory, s16f, dst, cand_cnt, cand_val, cand_idx);
  finalize_kernel<<<(BATCH + 255) / 256, 256, 0, stream>>>(src, dst, labels, ts,
                                                           cand_cnt, cand_val, cand_idx, out);
}

// Round 6
// 227.037 us; speedup vs baseline: 1.0191x; 1.0093x over previous
//
#include <hip/hip_runtime.h>

#define NUM_NODES 200000
#define DIM 128
#define BATCH 1024
#define K_NEG 5
#define CAP 16
#define JW 64             /* j-columns per wave (2 MFMA B-subtiles) */
#define BN (4 * JW)       /* j-columns per block = 256 */
#define JBLOCKS 782       /* ceil(200000/256); padded rows up to 200192 */
#define THRESH 0.7f
#define FILL (-1.0e9f)

typedef __attribute__((ext_vector_type(16))) float f32x16;

// ---------- float -> fp8 e4m3fn (OCP), RNE; |x| <= 1 in our use ----------
__device__ __forceinline__ unsigned char f2fp8(float x) {
  unsigned u = __builtin_bit_cast(unsigned, x);
  unsigned char s = (unsigned char)((u >> 24) & 0x80u);
  float ax = fabsf(x);
  unsigned char enc;
  if (ax < 0.015625f) {                 // < 2^-6: subnormal, lsb 2^-9
    enc = (unsigned char)(int)rintf(ax * 512.0f);   // 0..8; 8 rolls into exp=1 mant=0
  } else {
    int ee; float fr = frexpf(ax, &ee); // ax = fr * 2^ee, fr in [0.5,1)
    int E = ee + 6;                     // biased exponent (bias 7, fr=0.5 => exp ee-1)
    int mant = (int)rintf((fr * 2.0f - 1.0f) * 8.0f);  // 0..8; 8 rolls exp
    enc = (unsigned char)((E << 3) + mant);
  }
  return (unsigned char)(enc | s);
}

// ---------------- Threefry-2x32 (JAX-compatible) ----------------
__device__ __forceinline__ void tf2x32(unsigned k0, unsigned k1,
                                       unsigned x0, unsigned x1,
                                       unsigned* o0, unsigned* o1) {
  unsigned ks2 = k0 ^ k1 ^ 0x1BD11BDAu;
  unsigned v0 = x0 + k0, v1 = x1 + k1;
#define TFR(r) { v0 += v1; v1 = (v1 << r) | (v1 >> (32 - r)); v1 ^= v0; }
  TFR(13) TFR(15) TFR(26) TFR(6)   v0 += k1;  v1 += ks2 + 1u;
  TFR(17) TFR(29) TFR(16) TFR(24)  v0 += ks2; v1 += k0 + 2u;
  TFR(13) TFR(15) TFR(26) TFR(6)   v0 += k0;  v1 += k1 + 3u;
  TFR(17) TFR(29) TFR(16) TFR(24)  v0 += k1;  v1 += ks2 + 4u;
  TFR(13) TFR(15) TFR(26) TFR(6)   v0 += ks2; v1 += k0 + 5u;
#undef TFR
  *o0 = v0; *o1 = v1;
}

__device__ __forceinline__ unsigned rbits32(unsigned ka, unsigned kb, unsigned m) {
  unsigned o0, o1;
  tf2x32(ka, kb, 0u, m, &o0, &o1);
  return o0 ^ o1;
}

// Fragment mapping (fp8 32x32x16, 8 elems/lane, mirrors verified bf16 pattern):
// operand lane (l32 = lane&31, half = lane>>5) holds row/col = l32,
// k = ks*16 + half*8 + t (t=0..7). Storage: 8-B chunk per (tile, ks, lane);
// A additionally pairs ks (2kp, 2kp+1) into 16-B chunks for ds_read_b128.

// ---- kernel 1: src rows -> fp8 A-fragments; zero counters ----
__global__ void prep_a_kernel(const float* __restrict__ memory,
                              const int* __restrict__ src_nodes,
                              unsigned char* __restrict__ afragA,
                              int* __restrict__ cand_cnt) {
  int tid = threadIdx.x;
  int gid = blockIdx.x * 256 + tid;
  if (gid < BATCH) cand_cnt[gid] = 0;
  int row = blockIdx.x * 4 + (tid >> 6);   // 256 blocks x 4 rows
  int L = tid & 63;                        // lane owns cols 2L, 2L+1
  int s = src_nodes[row];
  float2 v = ((const float2*)(memory + (size_t)s * DIM))[L];
  float ss = v.x * v.x + v.y * v.y;
#pragma unroll
  for (int off = 32; off > 0; off >>= 1) ss += __shfl_xor(ss, off);
  float inv = 1.0f / fmaxf(sqrtf(ss), 1e-12f);
  unsigned char b0 = f2fp8(v.x * inv), b1 = f2fp8(v.y * inv);
  int ms = row >> 5, l32 = row & 31;
  int c = 2 * L;
  int kp = c >> 5, half = (c >> 3) & 1, tp = ((c >> 4) & 1) * 8 + (c & 7);
  size_t chunk = ((size_t)(ms * 4 + kp)) * 64 + half * 32 + l32;
  *(unsigned short*)(afragA + chunk * 16 + tp) =
      (unsigned short)((unsigned)b0 | ((unsigned)b1 << 8));
}

// ---- kernel 2: ALL node rows -> L2-normalized fp8 B-fragments (25.6 MB) ----
__global__ void prep_c_kernel(const float* __restrict__ memory,
                              unsigned long long* __restrict__ cfrag) {
  int tid = threadIdx.x;
  int wid = tid >> 6;
  int lane = tid & 63;
  int half = lane >> 5;
  int l32 = lane & 31;
  int rowbase = blockIdx.x * BN + wid * 64;
#pragma unroll
  for (int js = 0; js < 2; ++js) {
    int j = rowbase + js * 32 + l32;
    bool jv = (j < NUM_NODES);
    const float4* rp4 = (const float4*)(memory + (size_t)j * DIM);
    float4 q[16];
#pragma unroll
    for (int ks = 0; ks < 8; ++ks) {
      q[ks * 2]     = jv ? rp4[ks * 4 + half * 2]     : make_float4(0.f, 0.f, 0.f, 0.f);
      q[ks * 2 + 1] = jv ? rp4[ks * 4 + half * 2 + 1] : make_float4(0.f, 0.f, 0.f, 0.f);
    }
    float ss = 0.0f;
#pragma unroll
    for (int i = 0; i < 16; ++i)
      ss += q[i].x * q[i].x + q[i].y * q[i].y + q[i].z * q[i].z + q[i].w * q[i].w;
    ss += __shfl_xor(ss, 32);            // combine the two half-rows
    float inv = 1.0f / fmaxf(sqrtf(ss), 1e-12f);
#pragma unroll
    for (int ks = 0; ks < 8; ++ks) {
      float4 a = q[ks * 2], b = q[ks * 2 + 1];
      unsigned long long w =
          (unsigned long long)f2fp8(a.x * inv)
        | ((unsigned long long)f2fp8(a.y * inv) << 8)
        | ((unsigned long long)f2fp8(a.z * inv) << 16)
        | ((unsigned long long)f2fp8(a.w * inv) << 24)
        | ((unsigned long long)f2fp8(b.x * inv) << 32)
        | ((unsigned long long)f2fp8(b.y * inv) << 40)
        | ((unsigned long long)f2fp8(b.z * inv) << 48)
        | ((unsigned long long)f2fp8(b.w * inv) << 56);
      cfrag[((size_t)(j >> 5) * 8 + ks) * 64 + half * 32 + l32] = w;
    }
  }
}

// ---- kernel 3: fp8 MFMA sim scan; A in 32-KB LDS phases; 4 waves/SIMD ----
__global__ __launch_bounds__(256, 4) void sim_scan_kernel(
    const ulong2* __restrict__ afragG,       // 8192 16-B chunks (128 KB)
    const unsigned long long* __restrict__ cfrag,
    const int* __restrict__ dst_nodes,
    int* __restrict__ cand_cnt,
    float* __restrict__ cand_val,
    int* __restrict__ cand_idx) {
  __shared__ ulong2 aT[2048];   // 32 KB: one phase = 8 ms-subtiles of fp8 A
  int tid = threadIdx.x;
  int wid = tid >> 6;
  int lane = tid & 63;
  int half = lane >> 5;
  int l32 = lane & 31;
  int jb = blockIdx.x * BN + wid * JW;

  // B fragments: 16 coalesced 8-B loads, no math
  long bf[2][8];
#pragma unroll
  for (int js = 0; js < 2; ++js)
#pragma unroll
    for (int ks = 0; ks < 8; ++ks)
      bf[js][ks] = (long)cfrag[((size_t)((jb >> 5) + js) * 8 + ks) * 64 + lane];

  for (int p = 0; p < 4; ++p) {
    __syncthreads();
    const ulong2* g = afragG + p * 2048;
#pragma unroll
    for (int c = 0; c < 8; ++c) {
      int idx = c * 256 + tid;
      aT[idx] = g[idx];
    }
    __syncthreads();

#pragma unroll
    for (int ml = 0; ml < 8; ++ml) {
      int ms = p * 8 + ml;
      ulong2 av[4];
#pragma unroll
      for (int kp = 0; kp < 4; ++kp) av[kp] = aT[(ml * 4 + kp) * 64 + lane];
      f32x16 acc0, acc1;
#pragma unroll
      for (int i = 0; i < 16; ++i) { acc0[i] = 0.0f; acc1[i] = 0.0f; }
#pragma unroll
      for (int kp = 0; kp < 4; ++kp) {
        long alo = (long)av[kp].x;   // ks = 2*kp
        long ahi = (long)av[kp].y;   // ks = 2*kp+1
        acc0 = __builtin_amdgcn_mfma_f32_32x32x16_fp8_fp8(alo, bf[0][2 * kp], acc0, 0, 0, 0);
        acc1 = __builtin_amdgcn_mfma_f32_32x32x16_fp8_fp8(alo, bf[1][2 * kp], acc1, 0, 0, 0);
        acc0 = __builtin_amdgcn_mfma_f32_32x32x16_fp8_fp8(ahi, bf[0][2 * kp + 1], acc0, 0, 0, 0);
        acc1 = __builtin_amdgcn_mfma_f32_32x32x16_fp8_fp8(ahi, bf[1][2 * kp + 1], acc1, 0, 0, 0);
      }
      // hit gate: max over the 32 accumulator elements (rarely taken)
      float m[16];
#pragma unroll
      for (int i = 0; i < 16; ++i) m[i] = fmaxf(acc0[i], acc1[i]);
#pragma unroll
      for (int i = 0; i < 8; ++i) m[i] = fmaxf(m[i], m[i + 8]);
#pragma unroll
      for (int i = 0; i < 4; ++i) m[i] = fmaxf(m[i], m[i + 4]);
      float vm = fmaxf(fmaxf(m[0], m[1]), fmaxf(m[2], m[3]));
      if (vm > THRESH) {
        // C/D layout (m74/m101, dtype-independent): col=lane&31,
        // row = (reg&3) + 8*(reg>>2) + 4*(lane>>5)
#pragma unroll
        for (int js = 0; js < 2; ++js) {
          int gj = jb + js * 32 + l32;
#pragma unroll
          for (int r = 0; r < 16; ++r) {
            float v = (js == 0) ? acc0[r] : acc1[r];
            if (v > THRESH) {
              int gi = ms * 32 + (r & 3) + 8 * (r >> 2) + 4 * half;
              if (gj < NUM_NODES && gj != dst_nodes[gi]) {
                int pp = atomicAdd(&cand_cnt[gi], 1);
                if (pp < CAP) {
                  cand_val[gi * CAP + pp] = v;
                  cand_idx[gi * CAP + pp] = gj;
                }
              }
            }
          }
        }
      }
    }
  }
}

// ---- kernel 4: top-5 per row, threefry negatives, assemble ----
__global__ void finalize_kernel(const int* __restrict__ src_nodes,
                                const int* __restrict__ dst_nodes,
                                const float* __restrict__ labels,
                                const float* __restrict__ ts,
                                const int* __restrict__ cand_cnt,
                                const float* __restrict__ cand_val,
                                const int* __restrict__ cand_idx,
                                float* __restrict__ out) {
  int r = blockIdx.x * 256 + threadIdx.x;
  if (r >= BATCH) return;
  const int TOT = BATCH + BATCH * K_NEG;  // 6144
  int srcv = src_nodes[r];
  float tsv = ts[r];
  out[r] = (float)srcv;
  out[TOT + r] = (float)dst_nodes[r];
  float l = labels[r];
  out[2 * TOT + r] = l * 0.9f + (1.0f - l) * 0.1f;
  out[3 * TOT + r] = tsv;

  int cnt = cand_cnt[r];
  cnt = cnt < CAP ? cnt : CAP;
  float cv[CAP]; int ci[CAP];
  for (int i = 0; i < cnt; ++i) { cv[i] = cand_val[r * CAP + i]; ci[i] = cand_idx[r * CAP + i]; }

  // jax.random.split(key(42)) — partitionable/foldlike: k_i = threefry(key, 0, i)
  unsigned k1a, k1b, k2a, k2b;
  tf2x32(0u, 42u, 0u, 0u, &k1a, &k1b);
  tf2x32(0u, 42u, 0u, 1u, &k2a, &k2b);

  const unsigned span = 200000u;
  const unsigned mult = 167296u;  // 2^32 % span

  for (int s = 0; s < K_NEG; ++s) {
    int sel = -1;
    for (int i = 0; i < cnt; ++i)
      if (sel < 0 || cv[i] > cv[sel] || (cv[i] == cv[sel] && ci[i] < ci[sel])) sel = i;
    float v = FILL; int idx = 0;
    if (sel >= 0) { v = cv[sel]; idx = ci[sel]; cv[sel] = FILL; ci[sel] = 0x7fffffff; }
    bool is_real = v > (FILL + 1.0f);

    unsigned m = (unsigned)(r * K_NEG + s);
    unsigned hi = rbits32(k1a, k1b, m);
    unsigned lo = rbits32(k2a, k2b, m);
    unsigned off = ((hi % span) * mult + (lo % span)) % span;  // uint32 wrap, as JAX
    int rd = (int)off;
    if (rd == srcv) rd = (rd + 1) % NUM_NODES;
    int fd = is_real ? idx : rd;

    int mi = (int)m;
    out[BATCH + mi] = (float)srcv;
    out[TOT + BATCH + mi] = (float)fd;
    out[2 * TOT + BATCH + mi] = 0.1f;   // smoothing of label 0
    out[3 * TOT + BATCH + mi] = tsv;
    out[4 * TOT + mi] = v;
  }
}

extern "C" void kernel_launch(void* const* d_in, const int* in_sizes, int n_in,
                              void* d_out, int out_size, void* d_ws, size_t ws_size,
                              hipStream_t stream) {
  const int* src = (const int*)d_in[0];
  const int* dst = (const int*)d_in[1];
  const float* labels = (const float*)d_in[2];
  const float* ts = (const float*)d_in[3];
  const float* memory = (const float*)d_in[4];
  float* out = (float*)d_out;

  char* ws = (char*)d_ws;
  // cfrag: 782*256 padded rows x 128 fp8 = 25,624,576 B
  unsigned long long* cfrag = (unsigned long long*)ws;
  size_t off = (size_t)JBLOCKS * 256 * 128;
  unsigned char* afragA = (unsigned char*)(ws + off);   // 131072 B
  int* cand_cnt = (int*)(ws + off + 131072);            // 4096 B
  float* cand_val = (float*)(ws + off + 135168);        // 65536 B
  int* cand_idx = (int*)(ws + off + 200704);            // 65536 B

  prep_a_kernel<<<256, 256, 0, stream>>>(memory, src, afragA, cand_cnt);
  prep_c_kernel<<<JBLOCKS, 256, 0, stream>>>(memory, cfrag);
  sim_scan_kernel<<<JBLOCKS, 256, 0, stream>>>((const ulong2*)afragA, cfrag, dst,
                                               cand_cnt, cand_val, cand_idx);
  finalize_kernel<<<(BATCH + 255) / 256, 256, 0, stream>>>(src, dst, labels, ts,
                                                           cand_cnt, cand_val, cand_idx, out);
}